// Round 4
// baseline (126.778 us; speedup 1.0000x reference)
//
#include <hip/hip_runtime.h>

#define L   2048
#define NM  10
#define NG  20
#define NF  30

// fws layout (floats): tt[L], then float4 tab[NM*L] = {log2|cos|, log2|sin|, sin(phi), 0}
#define OFF_T   0
#define OFF_TAB 2048
#define FWS_FLOATS (OFF_TAB + 4*NM*L)   // 83968 floats

#define NBC 313   // ceil(80000/256)
#define NBF 106   // ceil(27000/256)

__device__ __forceinline__ float grid20(int i) {
  // jnp.logspace(-1,1,20)[i] = 10^(-1 + 2i/19)
  double e = -1.0 + 2.0 * (double)i / 19.0;
  return (float)exp2(e * 3.3219280948873623478703194294894);
}

__device__ __forceinline__ float finev(float c, int j) {
  // jnp.linspace(0.8c, 1.2c, 30)[j]
  return (float)((double)c * 0.8 + (double)j * ((double)c * 0.4 / 29.0));
}

// ---------------- K1: setup (block 0) + tables (blocks 1..80) --------------
__global__ __launch_bounds__(256) void k_init(const float* __restrict__ x,
                                              const int* __restrict__ freqp,
                                              float* __restrict__ fws,
                                              double* __restrict__ dws) {
  if (blockIdx.x == 0) {
    int tid = threadIdx.x;
    int lane = tid & 63, w = tid >> 6;
    __shared__ double sh[8];
    __shared__ double s_mean, s_d;

    double sx = 0.0, sxx = 0.0;
    for (int l = tid; l < L; l += 256) {
      double v = (double)x[l];
      sx += v; sxx += v * v;
    }
    for (int o = 32; o > 0; o >>= 1) { sx += __shfl_down(sx, o); sxx += __shfl_down(sxx, o); }
    if (lane == 0) { sh[w] = sx; sh[4 + w] = sxx; }
    __syncthreads();
    if (tid == 0) {
      sx = sh[0] + sh[1] + sh[2] + sh[3];
      sxx = sh[4] + sh[5] + sh[6] + sh[7];
      double mean = sx / (double)L;
      double S = sxx - sx * sx / (double)L; if (S < 0.0) S = 0.0;
      double sd = sqrt(S / (double)(L - 1));
      s_mean = mean; s_d = sd + 1e-6;
    }
    __syncthreads();
    double mean = s_mean, d = s_d;

    double st = 0.0, stt = 0.0;
    for (int l = tid; l < L; l += 256) {
      float tv = (float)(((double)x[l] - mean) / d);
      fws[OFF_T + l] = tv;
      st += (double)tv; stt += (double)tv * (double)tv;
    }
    for (int o = 32; o > 0; o >>= 1) { st += __shfl_down(st, o); stt += __shfl_down(stt, o); }
    __syncthreads();
    if (lane == 0) { sh[w] = st; sh[4 + w] = stt; }
    __syncthreads();
    if (tid == 0) {
      dws[0] = sh[0] + sh[1] + sh[2] + sh[3];
      dws[1] = sh[4] + sh[5] + sh[6] + sh[7];
    }
  } else {
    int idx = (blockIdx.x - 1) * 256 + threadIdx.x;   // [0, NM*L)
    if (idx < NM * L) {
      int m = idx / L, l = idx % L;
      double freq = (double)freqp[0];
      double t = -1.0 + 2.0 * (double)l / 2047.0;
      double phi = 6.2831853071795864769 * freq * t;
      double ang = (double)(m + 1) * phi * 0.25;
      double sv, cv;
      sincos(ang, &sv, &cv);
      float4 v;
      v.x = (float)log2(fabs(cv));
      v.y = (float)log2(fabs(sv));
      v.z = (float)sin(phi);
      v.w = 0.0f;
      reinterpret_cast<float4*>(fws + OFF_TAB)[m * L + l] = v;
    }
  }
}

// ---------------- K2: coarse partial sums ----------------------------------
// wave = (combo, i1ch, ec): combo=(m,i2,i3) in [0,4000); i1ch in {0,1} (10 i1);
// ec in {0,1} (1024 elems). 30 f32 accumulators per lane -> fits 64 VGPR.
__global__ __launch_bounds__(256) void k_coarse(const float* __restrict__ fws,
                                                float* __restrict__ part) {
  int gwid = (blockIdx.x * 256 + threadIdx.x) >> 6;   // [0, 16000)
  int lane = threadIdx.x & 63;
  int combo = gwid >> 2;
  int sub = gwid & 3;
  int i1ch = sub >> 1, ec = sub & 1;
  int m = combo / (NG * NG);
  int i23 = combo % (NG * NG);
  float n2 = grid20(i23 / NG), n3 = grid20(i23 % NG);

  float r[10];
#pragma unroll
  for (int q = 0; q < 10; q++) r[q] = -1.0f / grid20(i1ch * 10 + q);

  const float4* tab = reinterpret_cast<const float4*>(fws + OFF_TAB) + m * L;
  const float* tt = fws + OFF_T;

  float sg[10], sgg[10], sgt[10];
#pragma unroll
  for (int q = 0; q < 10; q++) { sg[q] = 0.0f; sgg[q] = 0.0f; sgt[q] = 0.0f; }

  int base = ec * 1024 + lane;
#pragma unroll 2
  for (int it = 0; it < 16; ++it) {
    int l = base + it * 64;
    float4 tb = tab[l];
    float tv = tt[l];
    float lsum = log2f(exp2f(n2 * tb.x) + exp2f(n3 * tb.y));
    float spv = tb.z;
#pragma unroll
    for (int q = 0; q < 10; q++) {
      float g = exp2f(r[q] * lsum) * spv;
      sg[q] += g;
      sgg[q] = fmaf(g, g, sgg[q]);
      sgt[q] = fmaf(g, tv, sgt[q]);
    }
  }

#pragma unroll
  for (int q = 0; q < 10; q++) {
    for (int o = 32; o > 0; o >>= 1) {
      sg[q]  += __shfl_down(sg[q],  o);
      sgg[q] += __shfl_down(sgg[q], o);
      sgt[q] += __shfl_down(sgt[q], o);
    }
  }
  if (lane == 0) {
    float* dst = part + gwid * 30;   // gwid = ((combo*2+i1ch)*2+ec)
#pragma unroll
    for (int q = 0; q < 10; q++) {
      dst[q * 3 + 0] = sg[q];
      dst[q * 3 + 1] = sgg[q];
      dst[q * 3 + 2] = sgt[q];
    }
  }
}

// ---------------- block argmin helper --------------------------------------
__device__ __forceinline__ void block_argmin_to0(double& best, int& bi,
                                                 double* sbv, int* sbi) {
  int lane = threadIdx.x & 63, w = threadIdx.x >> 6;
  for (int o = 32; o > 0; o >>= 1) {
    double ob = __shfl_down(best, o);
    int oi = __shfl_down(bi, o);
    if (ob < best || (ob == best && oi < bi)) { best = ob; bi = oi; }
  }
  if (lane == 0) { sbv[w] = best; sbi[w] = bi; }
  __syncthreads();
  if (threadIdx.x == 0) {
    for (int k = 1; k < 4; k++) {
      if (sbv[k] < best || (sbv[k] == best && sbi[k] < bi)) { best = sbv[k]; bi = sbi[k]; }
    }
  }
}

// ---------------- K3: coarse finalize + argmin stage 1 ---------------------
__global__ __launch_bounds__(256) void k_cfin(const float* __restrict__ part,
                                              const double* __restrict__ dws,
                                              double* __restrict__ pv,
                                              int* __restrict__ pi) {
  int t = blockIdx.x * 256 + threadIdx.x;
  double best = 1e300; int bi = 0x7fffffff;
  if (t < NM * NG * NG * NG) {
    int m = t / (NG * NG * NG);
    int i1 = (t / (NG * NG)) % NG;
    int i23 = t % (NG * NG);
    int combo = m * (NG * NG) + i23;
    int i1ch = i1 / 10, q = i1 % 10;
    const float* p0 = part + ((combo * 2 + i1ch) * 2) * 30 + q * 3;
    double sg  = (double)p0[0] + (double)p0[30];
    double sgg = (double)p0[1] + (double)p0[31];
    double sgt = (double)p0[2] + (double)p0[32];
    double sum_t = dws[0], sum_tt = dws[1];
    double mean = sg / (double)L;
    double S = sgg - sg * sg / (double)L; if (S < 0.0) S = 0.0;
    double d = sqrt(S / (double)(L - 1)) + 1e-6;
    best = (S / (d * d) - 2.0 * (sgt - mean * sum_t) / d + sum_tt) / (double)L;
    bi = t;
  }
  __shared__ double sbv[4];
  __shared__ int sbi[4];
  block_argmin_to0(best, bi, sbv, sbi);
  if (threadIdx.x == 0) { pv[blockIdx.x] = best; pi[blockIdx.x] = bi; }
}

// ---------------- K4: fine partial sums (in-block coarse argmin stage 2) ---
// wave = (fc=(j2,j3), j1ch in {0..4} (6 j1), ec in {0,1}); 18 accs per lane
__global__ __launch_bounds__(256) void k_fine(const float* __restrict__ fws,
                                              const double* __restrict__ pvc,
                                              const int* __restrict__ pic,
                                              float* __restrict__ partf) {
  __shared__ double sbv[4];
  __shared__ int sbi[4];
  __shared__ int s_ci;
  {
    double best = 1e300; int bi = 0x7fffffff;
    for (int i = threadIdx.x; i < NBC; i += 256) {
      double v = pvc[i]; int ix = pic[i];
      if (v < best || (v == best && ix < bi)) { best = v; bi = ix; }
    }
    block_argmin_to0(best, bi, sbv, sbi);
    if (threadIdx.x == 0) s_ci = bi;
  }
  __syncthreads();
  int ci = s_ci;
  int m  = ci / (NG * NG * NG);
  int rr = ci % (NG * NG * NG);
  float cn1 = grid20(rr / (NG * NG));
  float cn2 = grid20((rr / NG) % NG);
  float cn3 = grid20(rr % NG);

  int gwid = (blockIdx.x * 256 + threadIdx.x) >> 6;   // [0, 9000)
  int lane = threadIdx.x & 63;
  int fc = gwid / 10;
  int sub = gwid % 10;
  int j1ch = sub >> 1, ec = sub & 1;
  int j2 = fc / NF, j3 = fc % NF;
  float n2 = finev(cn2, j2), n3 = finev(cn3, j3);

  float r[6];
#pragma unroll
  for (int q = 0; q < 6; q++) r[q] = -1.0f / finev(cn1, j1ch * 6 + q);

  const float4* tab = reinterpret_cast<const float4*>(fws + OFF_TAB) + m * L;
  const float* tt = fws + OFF_T;

  float sg[6], sgg[6], sgt[6];
#pragma unroll
  for (int q = 0; q < 6; q++) { sg[q] = 0.0f; sgg[q] = 0.0f; sgt[q] = 0.0f; }

  int base = ec * 1024 + lane;
#pragma unroll 2
  for (int it = 0; it < 16; ++it) {
    int l = base + it * 64;
    float4 tb = tab[l];
    float tv = tt[l];
    float lsum = log2f(exp2f(n2 * tb.x) + exp2f(n3 * tb.y));
    float spv = tb.z;
#pragma unroll
    for (int q = 0; q < 6; q++) {
      float g = exp2f(r[q] * lsum) * spv;
      sg[q] += g;
      sgg[q] = fmaf(g, g, sgg[q]);
      sgt[q] = fmaf(g, tv, sgt[q]);
    }
  }

#pragma unroll
  for (int q = 0; q < 6; q++) {
    for (int o = 32; o > 0; o >>= 1) {
      sg[q]  += __shfl_down(sg[q],  o);
      sgg[q] += __shfl_down(sgg[q], o);
      sgt[q] += __shfl_down(sgt[q], o);
    }
  }
  if (lane == 0) {
    float* dst = partf + (size_t)gwid * 18;   // gwid = (fc*5+j1ch)*2+ec
#pragma unroll
    for (int q = 0; q < 6; q++) {
      dst[q * 3 + 0] = sg[q];
      dst[q * 3 + 1] = sgg[q];
      dst[q * 3 + 2] = sgt[q];
    }
  }
}

// ---------------- K5: fine finalize + argmin stage 1 -----------------------
__global__ __launch_bounds__(256) void k_ffin(const float* __restrict__ partf,
                                              const double* __restrict__ dws,
                                              double* __restrict__ pv,
                                              int* __restrict__ pi) {
  int t = blockIdx.x * 256 + threadIdx.x;   // reference fine flat index
  double best = 1e300; int bi = 0x7fffffff;
  if (t < NF * NF * NF) {
    int j1 = t / (NF * NF);
    int fc = t % (NF * NF);
    int j1ch = j1 / 6, q = j1 % 6;
    const float* p0 = partf + (size_t)((fc * 5 + j1ch) * 2) * 18 + q * 3;
    double sg  = (double)p0[0] + (double)p0[18];
    double sgg = (double)p0[1] + (double)p0[19];
    double sgt = (double)p0[2] + (double)p0[20];
    double sum_t = dws[0], sum_tt = dws[1];
    double mean = sg / (double)L;
    double S = sgg - sg * sg / (double)L; if (S < 0.0) S = 0.0;
    double d = sqrt(S / (double)(L - 1)) + 1e-6;
    best = (S / (d * d) - 2.0 * (sgt - mean * sum_t) / d + sum_tt) / (double)L;
    bi = t;
  }
  __shared__ double sbv[4];
  __shared__ int sbi[4];
  block_argmin_to0(best, bi, sbv, sbi);
  if (threadIdx.x == 0) { pv[blockIdx.x] = best; pi[blockIdx.x] = bi; }
}

// ---------------- K6: final argmins + emit ---------------------------------
__global__ __launch_bounds__(256) void k_out(const double* __restrict__ pvc,
                                             const int* __restrict__ pic,
                                             const double* __restrict__ pvf,
                                             const int* __restrict__ pif,
                                             float* __restrict__ out) {
  __shared__ double sbv[4];
  __shared__ int sbi[4];
  __shared__ int s_ci;

  {
    double best = 1e300; int bi = 0x7fffffff;
    for (int i = threadIdx.x; i < NBC; i += 256) {
      double v = pvc[i]; int ix = pic[i];
      if (v < best || (v == best && ix < bi)) { best = v; bi = ix; }
    }
    block_argmin_to0(best, bi, sbv, sbi);
    if (threadIdx.x == 0) s_ci = bi;
  }
  __syncthreads();
  {
    double best = 1e300; int bi = 0x7fffffff;
    for (int i = threadIdx.x; i < NBF; i += 256) {
      double v = pvf[i]; int ix = pif[i];
      if (v < best || (v == best && ix < bi)) { best = v; bi = ix; }
    }
    block_argmin_to0(best, bi, sbv, sbi);
    if (threadIdx.x == 0) {
      int ci = s_ci;
      int m  = ci / (NG * NG * NG);
      int rr = ci % (NG * NG * NG);
      float cn1 = grid20(rr / (NG * NG));
      float cn2 = grid20((rr / NG) % NG);
      float cn3 = grid20(rr % NG);
      int fi = bi;
      int f1 = fi / (NF * NF), f2 = (fi / NF) % NF, f3 = fi % NF;
      out[0] = (float)(m + 1);
      out[1] = finev(cn1, f1);
      out[2] = finev(cn2, f2);
      out[3] = finev(cn3, f3);
    }
  }
}

extern "C" void kernel_launch(void* const* d_in, const int* in_sizes, int n_in,
                              void* d_out, int out_size, void* d_ws, size_t ws_size,
                              hipStream_t stream) {
  const float* x = (const float*)d_in[0];
  const int* freqp = (const int*)d_in[1];
  float* out = (float*)d_out;

  float* fws = (float*)d_ws;
  double* dws = (double*)(fws + FWS_FLOATS);        // 2 doubles
  float* part_c = (float*)(dws + 2);                // 16000 * 30 = 480000 floats
  float* part_f = part_c + 480000;                  // 9000 * 18  = 162000 floats
  double* pvc = (double*)(part_f + 162000);         // NBC doubles
  double* pvf = pvc + NBC;                          // NBF doubles
  int* pic = (int*)(pvf + NBF);                     // NBC ints
  int* pif = pic + NBC;                             // NBF ints

  hipLaunchKernelGGL(k_init,   dim3(1 + (NM * L + 255) / 256), dim3(256), 0, stream,
                     x, freqp, fws, dws);
  hipLaunchKernelGGL(k_coarse, dim3(4000), dim3(256), 0, stream, fws, part_c);
  hipLaunchKernelGGL(k_cfin,   dim3(NBC),  dim3(256), 0, stream, part_c, dws, pvc, pic);
  hipLaunchKernelGGL(k_fine,   dim3(2250), dim3(256), 0, stream, fws, pvc, pic, part_f);
  hipLaunchKernelGGL(k_ffin,   dim3(NBF),  dim3(256), 0, stream, part_f, dws, pvf, pif);
  hipLaunchKernelGGL(k_out,    dim3(1),    dim3(256), 0, stream, pvc, pic, pvf, pif, out);
}

// Round 5
// 75.897 us; speedup vs baseline: 1.6704x; 1.6704x over previous
//
#include <hip/hip_runtime.h>

#define L    2048
#define HALF 1024
#define NM   10
#define NG   20
#define NF   30

// fws layout (floats): td[HALF], then float4 tab[NM*HALF] = {log2|cos|, log2|sin|, sin(phi), 0}
#define OFF_TD  0
#define OFF_TAB HALF
#define FWS_FLOATS (OFF_TAB + 4*NM*HALF)   // 1024 + 40960 = 41984 floats

#define NBC 313   // ceil(80000/256)
#define NBF 106   // ceil(27000/256)

__device__ __forceinline__ float grid20(int i) {
  // jnp.logspace(-1,1,20)[i] = 10^(-1 + 2i/19)
  double e = -1.0 + 2.0 * (double)i / 19.0;
  return (float)exp2(e * 3.3219280948873623478703194294894);
}

__device__ __forceinline__ float finev(float c, int j) {
  // jnp.linspace(0.8c, 1.2c, 30)[j]
  return (float)((double)c * 0.8 + (double)j * ((double)c * 0.4 / 29.0));
}

// ---------------- K1: setup (block 0) + tables (blocks 1..40) --------------
__global__ __launch_bounds__(256) void k_init(const float* __restrict__ x,
                                              const int* __restrict__ freqp,
                                              float* __restrict__ fws,
                                              double* __restrict__ dws) {
  if (blockIdx.x == 0) {
    int tid = threadIdx.x;
    int lane = tid & 63, w = tid >> 6;
    __shared__ double sh[8];
    __shared__ double s_mean, s_d;

    double sx = 0.0, sxx = 0.0;
    for (int l = tid; l < L; l += 256) {
      double v = (double)x[l];
      sx += v; sxx += v * v;
    }
    for (int o = 32; o > 0; o >>= 1) { sx += __shfl_down(sx, o); sxx += __shfl_down(sxx, o); }
    if (lane == 0) { sh[w] = sx; sh[4 + w] = sxx; }
    __syncthreads();
    if (tid == 0) {
      sx = sh[0] + sh[1] + sh[2] + sh[3];
      sxx = sh[4] + sh[5] + sh[6] + sh[7];
      double mean = sx / (double)L;
      double S = sxx - sx * sx / (double)L; if (S < 0.0) S = 0.0;
      double sd = sqrt(S / (double)(L - 1));
      s_mean = mean; s_d = sd + 1e-6;
    }
    __syncthreads();
    double mean = s_mean, d = s_d;

    // per pair: tv[l], tv[2047-l]; td = difference; accumulate both in sums
    double st = 0.0, stt = 0.0;
    for (int l = tid; l < HALF; l += 256) {
      float tva = (float)(((double)x[l] - mean) / d);
      float tvb = (float)(((double)x[L - 1 - l] - mean) / d);
      fws[OFF_TD + l] = tva - tvb;
      st += (double)tva + (double)tvb;
      stt += (double)tva * (double)tva + (double)tvb * (double)tvb;
    }
    for (int o = 32; o > 0; o >>= 1) { st += __shfl_down(st, o); stt += __shfl_down(stt, o); }
    __syncthreads();
    if (lane == 0) { sh[w] = st; sh[4 + w] = stt; }
    __syncthreads();
    if (tid == 0) {
      dws[0] = sh[0] + sh[1] + sh[2] + sh[3];
      dws[1] = sh[4] + sh[5] + sh[6] + sh[7];
    }
  } else {
    int idx = (blockIdx.x - 1) * 256 + threadIdx.x;   // [0, NM*HALF)
    if (idx < NM * HALF) {
      int m = idx / HALF, l = idx % HALF;
      double freq = (double)freqp[0];
      double t = -1.0 + 2.0 * (double)l / 2047.0;
      double phi = 6.2831853071795864769 * freq * t;
      double ang = (double)(m + 1) * phi * 0.25;
      double sv, cv;
      sincos(ang, &sv, &cv);
      float4 v;
      v.x = (float)log2(fabs(cv));
      v.y = (float)log2(fabs(sv));
      v.z = (float)sin(phi);
      v.w = 0.0f;
      reinterpret_cast<float4*>(fws + OFF_TAB)[m * HALF + l] = v;
    }
  }
}

// ---------------- K2: coarse partial sums (symmetry-halved) ----------------
// wave = (combo, i1ch): combo=(m,i2,i3) in [0,4000); i1ch in {0,1} (10 i1).
// per lane: 10 x {sgg, sgt} = 20 f32 accumulators; 1024 pairs, 16 iters.
__global__ __launch_bounds__(256, 1) void k_coarse(const float* __restrict__ fws,
                                                   float* __restrict__ part) {
  int gwid = (blockIdx.x * 256 + threadIdx.x) >> 6;   // [0, 8000)
  int lane = threadIdx.x & 63;
  int combo = gwid >> 1, i1ch = gwid & 1;
  int m = combo / (NG * NG);
  int i23 = combo % (NG * NG);
  float n2 = grid20(i23 / NG), n3 = grid20(i23 % NG);

  float r[10];
#pragma unroll
  for (int q = 0; q < 10; q++) r[q] = -1.0f / grid20(i1ch * 10 + q);

  const float4* tab = reinterpret_cast<const float4*>(fws + OFF_TAB) + m * HALF;
  const float* td = fws + OFF_TD;

  float sgg[10], sgt[10];
#pragma unroll
  for (int q = 0; q < 10; q++) { sgg[q] = 0.0f; sgt[q] = 0.0f; }

#pragma unroll 2
  for (int it = 0; it < 16; ++it) {
    int l = lane + it * 64;
    float4 tb = tab[l];
    float tdv = td[l];
    float lsum = log2f(exp2f(n2 * tb.x) + exp2f(n3 * tb.y));
    float spv = tb.z;
#pragma unroll
    for (int q = 0; q < 10; q++) {
      float g = exp2f(r[q] * lsum) * spv;
      sgg[q] = fmaf(g, g, sgg[q]);
      sgt[q] = fmaf(g, tdv, sgt[q]);
    }
  }

#pragma unroll
  for (int q = 0; q < 10; q++) {
    for (int o = 32; o > 0; o >>= 1) {
      sgg[q] += __shfl_down(sgg[q], o);
      sgt[q] += __shfl_down(sgt[q], o);
    }
  }
  if (lane == 0) {
    float* dst = part + gwid * 20;
#pragma unroll
    for (int q = 0; q < 10; q++) {
      dst[q * 2 + 0] = sgg[q];
      dst[q * 2 + 1] = sgt[q];
    }
  }
}

// ---------------- block argmin helper --------------------------------------
__device__ __forceinline__ void block_argmin_to0(double& best, int& bi,
                                                 double* sbv, int* sbi) {
  int lane = threadIdx.x & 63, w = threadIdx.x >> 6;
  for (int o = 32; o > 0; o >>= 1) {
    double ob = __shfl_down(best, o);
    int oi = __shfl_down(bi, o);
    if (ob < best || (ob == best && oi < bi)) { best = ob; bi = oi; }
  }
  if (lane == 0) { sbv[w] = best; sbi[w] = bi; }
  __syncthreads();
  if (threadIdx.x == 0) {
    for (int k = 1; k < 4; k++) {
      if (sbv[k] < best || (sbv[k] == best && sbi[k] < bi)) { best = sbv[k]; bi = sbi[k]; }
    }
  }
}

// mse from pair-sums: sg == 0 exactly (antisymmetry), S = 2*sgg_pairs
__device__ __forceinline__ double mse_from(double sgg2, double sgt, double sum_tt) {
  double S = sgg2; if (S < 0.0) S = 0.0;
  double d = sqrt(S / (double)(L - 1)) + 1e-6;
  return (S / (d * d) - 2.0 * sgt / d + sum_tt) / (double)L;
}

// ---------------- K3: coarse finalize + argmin stage 1 ---------------------
__global__ __launch_bounds__(256) void k_cfin(const float* __restrict__ part,
                                              const double* __restrict__ dws,
                                              double* __restrict__ pv,
                                              int* __restrict__ pi) {
  int t = blockIdx.x * 256 + threadIdx.x;
  double best = 1e300; int bi = 0x7fffffff;
  if (t < NM * NG * NG * NG) {
    int m = t / (NG * NG * NG);
    int i1 = (t / (NG * NG)) % NG;
    int i23 = t % (NG * NG);
    int combo = m * (NG * NG) + i23;
    int gwid = combo * 2 + i1 / 10, q = i1 % 10;
    const float* p0 = part + gwid * 20 + q * 2;
    best = mse_from(2.0 * (double)p0[0], (double)p0[1], dws[1]);
    bi = t;
  }
  __shared__ double sbv[4];
  __shared__ int sbi[4];
  block_argmin_to0(best, bi, sbv, sbi);
  if (threadIdx.x == 0) { pv[blockIdx.x] = best; pi[blockIdx.x] = bi; }
}

// ---------------- K4: fine partial sums (in-block coarse argmin stage 2) ---
// wave = (fc=(j2,j3), j1ch in {0..4}): 6 j1 x {sgg,sgt} = 12 accs; 1024 pairs
__global__ __launch_bounds__(256, 1) void k_fine(const float* __restrict__ fws,
                                                 const double* __restrict__ pvc,
                                                 const int* __restrict__ pic,
                                                 float* __restrict__ partf) {
  __shared__ double sbv[4];
  __shared__ int sbi[4];
  __shared__ int s_ci;
  {
    double best = 1e300; int bi = 0x7fffffff;
    for (int i = threadIdx.x; i < NBC; i += 256) {
      double v = pvc[i]; int ix = pic[i];
      if (v < best || (v == best && ix < bi)) { best = v; bi = ix; }
    }
    block_argmin_to0(best, bi, sbv, sbi);
    if (threadIdx.x == 0) s_ci = bi;
  }
  __syncthreads();
  int ci = s_ci;
  int m  = ci / (NG * NG * NG);
  int rr = ci % (NG * NG * NG);
  float cn1 = grid20(rr / (NG * NG));
  float cn2 = grid20((rr / NG) % NG);
  float cn3 = grid20(rr % NG);

  int gwid = (blockIdx.x * 256 + threadIdx.x) >> 6;   // [0, 4500)
  int lane = threadIdx.x & 63;
  int fc = gwid / 5;
  int j1ch = gwid % 5;
  int j2 = fc / NF, j3 = fc % NF;
  float n2 = finev(cn2, j2), n3 = finev(cn3, j3);

  float r[6];
#pragma unroll
  for (int q = 0; q < 6; q++) r[q] = -1.0f / finev(cn1, j1ch * 6 + q);

  const float4* tab = reinterpret_cast<const float4*>(fws + OFF_TAB) + m * HALF;
  const float* td = fws + OFF_TD;

  float sgg[6], sgt[6];
#pragma unroll
  for (int q = 0; q < 6; q++) { sgg[q] = 0.0f; sgt[q] = 0.0f; }

#pragma unroll 2
  for (int it = 0; it < 16; ++it) {
    int l = lane + it * 64;
    float4 tb = tab[l];
    float tdv = td[l];
    float lsum = log2f(exp2f(n2 * tb.x) + exp2f(n3 * tb.y));
    float spv = tb.z;
#pragma unroll
    for (int q = 0; q < 6; q++) {
      float g = exp2f(r[q] * lsum) * spv;
      sgg[q] = fmaf(g, g, sgg[q]);
      sgt[q] = fmaf(g, tdv, sgt[q]);
    }
  }

#pragma unroll
  for (int q = 0; q < 6; q++) {
    for (int o = 32; o > 0; o >>= 1) {
      sgg[q] += __shfl_down(sgg[q], o);
      sgt[q] += __shfl_down(sgt[q], o);
    }
  }
  if (lane == 0) {
    float* dst = partf + gwid * 12;
#pragma unroll
    for (int q = 0; q < 6; q++) {
      dst[q * 2 + 0] = sgg[q];
      dst[q * 2 + 1] = sgt[q];
    }
  }
}

// ---------------- K5: fine finalize + argmin stage 1 -----------------------
__global__ __launch_bounds__(256) void k_ffin(const float* __restrict__ partf,
                                              const double* __restrict__ dws,
                                              double* __restrict__ pv,
                                              int* __restrict__ pi) {
  int t = blockIdx.x * 256 + threadIdx.x;   // reference fine flat index
  double best = 1e300; int bi = 0x7fffffff;
  if (t < NF * NF * NF) {
    int j1 = t / (NF * NF);
    int fc = t % (NF * NF);
    int gwid = fc * 5 + j1 / 6, q = j1 % 6;
    const float* p0 = partf + gwid * 12 + q * 2;
    best = mse_from(2.0 * (double)p0[0], (double)p0[1], dws[1]);
    bi = t;
  }
  __shared__ double sbv[4];
  __shared__ int sbi[4];
  block_argmin_to0(best, bi, sbv, sbi);
  if (threadIdx.x == 0) { pv[blockIdx.x] = best; pi[blockIdx.x] = bi; }
}

// ---------------- K6: final argmins + emit ---------------------------------
__global__ __launch_bounds__(256) void k_out(const double* __restrict__ pvc,
                                             const int* __restrict__ pic,
                                             const double* __restrict__ pvf,
                                             const int* __restrict__ pif,
                                             float* __restrict__ out) {
  __shared__ double sbv[4];
  __shared__ int sbi[4];
  __shared__ int s_ci;

  {
    double best = 1e300; int bi = 0x7fffffff;
    for (int i = threadIdx.x; i < NBC; i += 256) {
      double v = pvc[i]; int ix = pic[i];
      if (v < best || (v == best && ix < bi)) { best = v; bi = ix; }
    }
    block_argmin_to0(best, bi, sbv, sbi);
    if (threadIdx.x == 0) s_ci = bi;
  }
  __syncthreads();
  {
    double best = 1e300; int bi = 0x7fffffff;
    for (int i = threadIdx.x; i < NBF; i += 256) {
      double v = pvf[i]; int ix = pif[i];
      if (v < best || (v == best && ix < bi)) { best = v; bi = ix; }
    }
    block_argmin_to0(best, bi, sbv, sbi);
    if (threadIdx.x == 0) {
      int ci = s_ci;
      int m  = ci / (NG * NG * NG);
      int rr = ci % (NG * NG * NG);
      float cn1 = grid20(rr / (NG * NG));
      float cn2 = grid20((rr / NG) % NG);
      float cn3 = grid20(rr % NG);
      int fi = bi;
      int f1 = fi / (NF * NF), f2 = (fi / NF) % NF, f3 = fi % NF;
      out[0] = (float)(m + 1);
      out[1] = finev(cn1, f1);
      out[2] = finev(cn2, f2);
      out[3] = finev(cn3, f3);
    }
  }
}

extern "C" void kernel_launch(void* const* d_in, const int* in_sizes, int n_in,
                              void* d_out, int out_size, void* d_ws, size_t ws_size,
                              hipStream_t stream) {
  const float* x = (const float*)d_in[0];
  const int* freqp = (const int*)d_in[1];
  float* out = (float*)d_out;

  float* fws = (float*)d_ws;
  double* dws = (double*)(fws + FWS_FLOATS);        // byte offset 167936, 8-aligned
  float* part_c = (float*)(dws + 2);                // 8000 * 20 = 160000 floats
  float* part_f = part_c + 160000;                  // 4500 * 12 = 54000 floats
  double* pvc = (double*)(part_f + 54000);          // NBC doubles (8-aligned)
  double* pvf = pvc + NBC;                          // NBF doubles
  int* pic = (int*)(pvf + NBF);                     // NBC ints
  int* pif = pic + NBC;                             // NBF ints

  hipLaunchKernelGGL(k_init,   dim3(1 + (NM * HALF + 255) / 256), dim3(256), 0, stream,
                     x, freqp, fws, dws);
  hipLaunchKernelGGL(k_coarse, dim3(2000), dim3(256), 0, stream, fws, part_c);
  hipLaunchKernelGGL(k_cfin,   dim3(NBC),  dim3(256), 0, stream, part_c, dws, pvc, pic);
  hipLaunchKernelGGL(k_fine,   dim3(1125), dim3(256), 0, stream, fws, pvc, pic, part_f);
  hipLaunchKernelGGL(k_ffin,   dim3(NBF),  dim3(256), 0, stream, part_f, dws, pvf, pif);
  hipLaunchKernelGGL(k_out,    dim3(1),    dim3(256), 0, stream, pvc, pic, pvf, pif, out);
}